// Round 3
// baseline (168.398 us; speedup 1.0000x reference)
//
#include <hip/hip_runtime.h>

#define HH 128
#define WW 128
#define BB 4
#define CC 64
#define CHN 21
#define NPIX (HH*WW)     // 16384
#define NTAP 24
#define PAD 4
#define PW 136
#define PH 136
#define PPLANE (PW*PH)   // 18496
#define PWQ (PW/4)       // 34

__device__ __forceinline__ int clampi(int v, int lo, int hi) {
    return v < lo ? lo : (v > hi ? hi : v);
}

// ---- pad: edge-replicate [*, 128,128] -> [*, 136,136], one float4 per thread
__global__ __launch_bounds__(256) void pad_kernel(
    const float* __restrict__ src, float* __restrict__ dst, int nplanes) {
    int t = blockIdx.x * blockDim.x + threadIdx.x;
    int total = nplanes * PH * PWQ;
    if (t >= total) return;
    int q = t % PWQ;
    int rest = t / PWQ;
    int ph = rest % PH;
    int pl = rest / PH;
    const float* sp = src + (size_t)pl * NPIX + (size_t)clampi(ph - PAD, 0, HH - 1) * WW;
    float4 v;
    v.x = sp[clampi(q * 4 + 0 - PAD, 0, WW - 1)];
    v.y = sp[clampi(q * 4 + 1 - PAD, 0, WW - 1)];
    v.z = sp[clampi(q * 4 + 2 - PAD, 0, WW - 1)];
    v.w = sp[clampi(q * 4 + 3 - PAD, 0, WW - 1)];
    *((float4*)(dst + (size_t)pl * PPLANE + (size_t)ph * PW + q * 4)) = v;
}

// ---- affinity partial: 2 pixels/thread, channels [g*cpg, (g+1)*cpg) --------
__global__ __launch_bounds__(256) void partial_affinity_kernel(
    const float* __restrict__ pfeats, float* __restrict__ partial, int cpg) {
    int t = blockIdx.x * blockDim.x + threadIdx.x;   // 0..32767
    int g = blockIdx.y;
    int w0 = (t & 63) * 2;
    int h = (t >> 6) & 127;
    int b = t >> 13;

    float acc[48];
    #pragma unroll
    for (int k = 0; k < 48; ++k) acc[k] = 0.f;

    int c0 = g * cpg;
    for (int c = c0; c < c0 + cpg; ++c) {
        const float* cp = pfeats + (size_t)(b * CC + c) * PPLANE;
        float tmp[48];
        float rb[10];
        float q0, q1, sum0, sum1, ss0, ss1;

#define ALOADROW(dy) { \
        const float2* rp = (const float2*)(cp + (size_t)(h + PAD + (dy)) * PW + w0); \
        float2 a0 = rp[0], a1 = rp[1], a2 = rp[2], a3 = rp[3], a4 = rp[4]; \
        rb[0]=a0.x; rb[1]=a0.y; rb[2]=a1.x; rb[3]=a1.y; rb[4]=a2.x; \
        rb[5]=a2.y; rb[6]=a3.x; rb[7]=a3.y; rb[8]=a4.x; rb[9]=a4.y; }

#define ATAP(k, di) { \
        float v0 = rb[(di)], v1 = rb[(di)+1]; \
        tmp[2*(k)]   = fabsf(v0 - q0); \
        tmp[2*(k)+1] = fabsf(v1 - q1); \
        sum0 += v0; ss0 = fmaf(v0, v0, ss0); \
        sum1 += v1; ss1 = fmaf(v1, v1, ss1); }

        ALOADROW(0);
        q0 = rb[4]; q1 = rb[5];
        sum0 = 3.f * q0; ss0 = 3.f * q0 * q0;
        sum1 = 3.f * q1; ss1 = 3.f * q1 * q1;
        ATAP(3,3)  ATAP(4,5)  ATAP(11,2) ATAP(12,6) ATAP(19,0) ATAP(20,8)
        ALOADROW(-1); ATAP(0,3)  ATAP(1,4)  ATAP(2,5)
        ALOADROW(1);  ATAP(5,3)  ATAP(6,4)  ATAP(7,5)
        ALOADROW(-2); ATAP(8,2)  ATAP(9,4)  ATAP(10,6)
        ALOADROW(2);  ATAP(13,2) ATAP(14,4) ATAP(15,6)
        ALOADROW(-4); ATAP(16,0) ATAP(17,4) ATAP(18,8)
        ALOADROW(4);  ATAP(21,0) ATAP(22,4) ATAP(23,8)

        float var0 = (ss0 - sum0 * sum0 * (1.f/27.f)) * (1.f/26.f);
        float var1 = (ss1 - sum1 * sum1 * (1.f/27.f)) * (1.f/26.f);
        float inv0 = 1.f / (1e-8f + 0.1f * sqrtf(fmaxf(var0, 0.f)));
        float inv1 = 1.f / (1e-8f + 0.1f * sqrtf(fmaxf(var1, 0.f)));
        #pragma unroll
        for (int k = 0; k < NTAP; ++k) {
            acc[2*k]   = fmaf(tmp[2*k],   -inv0, acc[2*k]);
            acc[2*k+1] = fmaf(tmp[2*k+1], -inv1, acc[2*k+1]);
        }
    }

    int pix = h * WW + w0;
    float* pb = partial + (size_t)(g * BB + b) * NTAP * NPIX + pix;
    #pragma unroll
    for (int k = 0; k < NTAP; ++k) {
        *((float2*)(pb + (size_t)k * NPIX)) = make_float2(acc[2*k], acc[2*k+1]);
    }
}

// ---- finalize: sum groups, mean over C, softmax over taps ------------------
__global__ __launch_bounds__(64) void finalize_affinity_kernel(
    const float* __restrict__ partial, float* __restrict__ aff, int G) {
    int idx = blockIdx.x * 64 + threadIdx.x;   // 0..65535
    int b = idx >> 14;
    int pix = idx & (NPIX - 1);
    float acc[NTAP];
    #pragma unroll
    for (int k = 0; k < NTAP; ++k) acc[k] = 0.f;
    for (int g = 0; g < G; ++g) {
        const float* pb = partial + (size_t)(g * BB + b) * NTAP * NPIX + pix;
        #pragma unroll
        for (int k = 0; k < NTAP; ++k) acc[k] += pb[(size_t)k * NPIX];
    }
    float m = -1e30f;
    #pragma unroll
    for (int k = 0; k < NTAP; ++k) { acc[k] *= (1.f/CC); m = fmaxf(m, acc[k]); }
    float s = 0.f;
    #pragma unroll
    for (int k = 0; k < NTAP; ++k) { acc[k] = expf(acc[k] - m); s += acc[k]; }
    float invs = 1.f / s;
    float* ab = aff + (size_t)b * NTAP * NPIX + pix;
    #pragma unroll
    for (int k = 0; k < NTAP; ++k) ab[(size_t)k * NPIX] = acc[k] * invs;
}

// ---- prop: 4 pixels/thread, one (b, ch) plane per block --------------------
__global__ __launch_bounds__(256) void prop_kernel(
    const float* __restrict__ psrc_all, const float* __restrict__ aff,
    float* __restrict__ dst, int final_iter) {
    int t = blockIdx.x * 256 + threadIdx.x;   // 0..4095
    int ch = blockIdx.y;
    int b = blockIdx.z;
    int w4 = t & 31;
    int w0 = w4 * 4;
    int h = t >> 5;

    const float* psrc = psrc_all + (size_t)(b * CHN + ch) * PPLANE;
    const float* affp = aff + (size_t)b * NTAP * NPIX + h * WW + w0;

    float4 acc = make_float4(0.f, 0.f, 0.f, 0.f);
    float rb[12];

#define PLOADROW(dy) { \
    const float4* rp = (const float4*)(psrc + (size_t)(h + PAD + (dy)) * PW + w0); \
    float4 f0 = rp[0], f1 = rp[1], f2 = rp[2]; \
    rb[0]=f0.x; rb[1]=f0.y; rb[2]=f0.z; rb[3]=f0.w; \
    rb[4]=f1.x; rb[5]=f1.y; rb[6]=f1.z; rb[7]=f1.w; \
    rb[8]=f2.x; rb[9]=f2.y; rb[10]=f2.z; rb[11]=f2.w; }

#define PTAP(k, di) { \
    float4 a = *((const float4*)(affp + (size_t)(k) * NPIX)); \
    acc.x = fmaf(a.x, rb[(di)],   acc.x); \
    acc.y = fmaf(a.y, rb[(di)+1], acc.y); \
    acc.z = fmaf(a.z, rb[(di)+2], acc.z); \
    acc.w = fmaf(a.w, rb[(di)+3], acc.w); }

    PLOADROW(0);  PTAP(3,3)  PTAP(4,5)  PTAP(11,2) PTAP(12,6) PTAP(19,0) PTAP(20,8)
    PLOADROW(-1); PTAP(0,3)  PTAP(1,4)  PTAP(2,5)
    PLOADROW(1);  PTAP(5,3)  PTAP(6,4)  PTAP(7,5)
    PLOADROW(-2); PTAP(8,2)  PTAP(9,4)  PTAP(10,6)
    PLOADROW(2);  PTAP(13,2) PTAP(14,4) PTAP(15,6)
    PLOADROW(-4); PTAP(16,0) PTAP(17,4) PTAP(18,8)
    PLOADROW(4);  PTAP(21,0) PTAP(22,4) PTAP(23,8)

    if (final_iter) {
        *((float4*)(dst + (size_t)(b * CHN + ch) * NPIX + h * WW + w0)) = acc;
    } else {
        float4* pd = (float4*)(dst + (size_t)(b * CHN + ch) * PPLANE);
        pd[(h + PAD) * PWQ + w4 + 1] = acc;
        if (h == 0) {
            #pragma unroll
            for (int r = 0; r < PAD; ++r) pd[r * PWQ + w4 + 1] = acc;
        }
        if (h == HH - 1) {
            #pragma unroll
            for (int r = 0; r < PAD; ++r) pd[(PH - 1 - r) * PWQ + w4 + 1] = acc;
        }
        if (w4 == 0) {
            float4 e = make_float4(acc.x, acc.x, acc.x, acc.x);
            pd[(h + PAD) * PWQ] = e;
            if (h == 0) {
                #pragma unroll
                for (int r = 0; r < PAD; ++r) pd[r * PWQ] = e;
            }
            if (h == HH - 1) {
                #pragma unroll
                for (int r = 0; r < PAD; ++r) pd[(PH - 1 - r) * PWQ] = e;
            }
        }
        if (w4 == 31) {
            float4 e = make_float4(acc.w, acc.w, acc.w, acc.w);
            pd[(h + PAD) * PWQ + PWQ - 1] = e;
            if (h == 0) {
                #pragma unroll
                for (int r = 0; r < PAD; ++r) pd[r * PWQ + PWQ - 1] = e;
            }
            if (h == HH - 1) {
                #pragma unroll
                for (int r = 0; r < PAD; ++r) pd[(PH - 1 - r) * PWQ + PWQ - 1] = e;
            }
        }
    }
}

extern "C" void kernel_launch(void* const* d_in, const int* in_sizes, int n_in,
                              void* d_out, int out_size, void* d_ws, size_t ws_size,
                              hipStream_t stream) {
    const float* feats = (const float*)d_in[0];
    const float* mask  = (const float*)d_in[1];
    float* out = (float*)d_out;

    const size_t affE    = (size_t)BB * NTAP * NPIX;    // 1.57 M floats
    const size_t pbufE   = (size_t)BB * CHN * PPLANE;   // 1.55 M floats
    const size_t pfeatsE = (size_t)BB * CC * PPLANE;    // 4.73 M floats

    float* aff     = (float*)d_ws;
    float* pbuf0   = aff + affE;
    float* pbuf1   = pbuf0 + pbufE;
    float* pfeats  = pbuf1 + pbufE;
    float* partial = pfeats + pfeatsE;

    size_t baseBytes = (affE + 2 * pbufE + pfeatsE) * sizeof(float);
    int G = 1;
    for (int g = 8; g >= 1; g >>= 1) {
        if (baseBytes + (size_t)g * affE * sizeof(float) <= ws_size) { G = g; break; }
    }

    {
        int total = BB * CC * PH * PWQ;
        pad_kernel<<<dim3((total + 255) / 256), dim3(256), 0, stream>>>(feats, pfeats, BB * CC);
    }
    partial_affinity_kernel<<<dim3(128, G), dim3(256), 0, stream>>>(pfeats, partial, CC / G);
    finalize_affinity_kernel<<<dim3(1024), dim3(64), 0, stream>>>(partial, aff, G);
    {
        int total = BB * CHN * PH * PWQ;
        pad_kernel<<<dim3((total + 255) / 256), dim3(256), 0, stream>>>(mask, pbuf0, BB * CHN);
    }

    const float* src = pbuf0;
    for (int it = 1; it <= 10; ++it) {
        if (it < 10) {
            float* dst = (it & 1) ? pbuf1 : pbuf0;
            prop_kernel<<<dim3(16, CHN, BB), dim3(256), 0, stream>>>(src, aff, dst, 0);
            src = dst;
        } else {
            prop_kernel<<<dim3(16, CHN, BB), dim3(256), 0, stream>>>(src, aff, out, 1);
        }
    }
}

// Round 4
// 165.390 us; speedup vs baseline: 1.0182x; 1.0182x over previous
//
#include <hip/hip_runtime.h>

#define HH 128
#define WW 128
#define BB 4
#define CC 64
#define CHN 21
#define NPIX (HH*WW)     // 16384
#define NTAP 24
#define PAD 4
#define PW 136
#define PH 136
#define PPLANE (PW*PH)   // 18496
#define PWQ (PW/4)       // 34
#define CG 3             // channels per prop thread
#define NCG (CHN/CG)     // 7

__device__ __forceinline__ int clampi(int v, int lo, int hi) {
    return v < lo ? lo : (v > hi ? hi : v);
}

// ---- pad: edge-replicate feats AND mask into padded planes in one launch ---
__global__ __launch_bounds__(256) void pad_kernel(
    const float* __restrict__ feats, const float* __restrict__ mask,
    float* __restrict__ pfeats, float* __restrict__ pmask) {
    int t = blockIdx.x * blockDim.x + threadIdx.x;
    const int nfp = BB * CC;
    const int total = (nfp + BB * CHN) * PH * PWQ;
    if (t >= total) return;
    int q = t % PWQ;
    int rest = t / PWQ;
    int ph = rest % PH;
    int pl = rest / PH;
    const float* src;
    float* dst;
    if (pl < nfp) { src = feats + (size_t)pl * NPIX; dst = pfeats + (size_t)pl * PPLANE; }
    else { src = mask + (size_t)(pl - nfp) * NPIX; dst = pmask + (size_t)(pl - nfp) * PPLANE; }
    const float* sp = src + (size_t)clampi(ph - PAD, 0, HH - 1) * WW;
    float4 v;
    v.x = sp[clampi(q * 4 + 0 - PAD, 0, WW - 1)];
    v.y = sp[clampi(q * 4 + 1 - PAD, 0, WW - 1)];
    v.z = sp[clampi(q * 4 + 2 - PAD, 0, WW - 1)];
    v.w = sp[clampi(q * 4 + 3 - PAD, 0, WW - 1)];
    *((float4*)(dst + (size_t)ph * PW + q * 4)) = v;
}

// ---- affinity partial: 2 pixels/thread, channels [g*cpg, (g+1)*cpg) --------
__global__ __launch_bounds__(256) void partial_affinity_kernel(
    const float* __restrict__ pfeats, float* __restrict__ partial, int cpg) {
    int t = blockIdx.x * blockDim.x + threadIdx.x;   // 0..32767
    int g = blockIdx.y;
    int w0 = (t & 63) * 2;
    int h = (t >> 6) & 127;
    int b = t >> 13;

    float acc[48];
    #pragma unroll
    for (int k = 0; k < 48; ++k) acc[k] = 0.f;

    int c0 = g * cpg;
    for (int c = c0; c < c0 + cpg; ++c) {
        const float* cp = pfeats + (size_t)(b * CC + c) * PPLANE;
        float tmp[48];
        float rb[10];
        float q0, q1, sum0, sum1, ss0, ss1;

#define ALOADROW(dy) { \
        const float2* rp = (const float2*)(cp + (size_t)(h + PAD + (dy)) * PW + w0); \
        float2 a0 = rp[0], a1 = rp[1], a2 = rp[2], a3 = rp[3], a4 = rp[4]; \
        rb[0]=a0.x; rb[1]=a0.y; rb[2]=a1.x; rb[3]=a1.y; rb[4]=a2.x; \
        rb[5]=a2.y; rb[6]=a3.x; rb[7]=a3.y; rb[8]=a4.x; rb[9]=a4.y; }

#define ATAP(k, di) { \
        float v0 = rb[(di)], v1 = rb[(di)+1]; \
        tmp[2*(k)]   = fabsf(v0 - q0); \
        tmp[2*(k)+1] = fabsf(v1 - q1); \
        sum0 += v0; ss0 = fmaf(v0, v0, ss0); \
        sum1 += v1; ss1 = fmaf(v1, v1, ss1); }

        ALOADROW(0);
        q0 = rb[4]; q1 = rb[5];
        sum0 = 3.f * q0; ss0 = 3.f * q0 * q0;
        sum1 = 3.f * q1; ss1 = 3.f * q1 * q1;
        ATAP(3,3)  ATAP(4,5)  ATAP(11,2) ATAP(12,6) ATAP(19,0) ATAP(20,8)
        ALOADROW(-1); ATAP(0,3)  ATAP(1,4)  ATAP(2,5)
        ALOADROW(1);  ATAP(5,3)  ATAP(6,4)  ATAP(7,5)
        ALOADROW(-2); ATAP(8,2)  ATAP(9,4)  ATAP(10,6)
        ALOADROW(2);  ATAP(13,2) ATAP(14,4) ATAP(15,6)
        ALOADROW(-4); ATAP(16,0) ATAP(17,4) ATAP(18,8)
        ALOADROW(4);  ATAP(21,0) ATAP(22,4) ATAP(23,8)

        float var0 = (ss0 - sum0 * sum0 * (1.f/27.f)) * (1.f/26.f);
        float var1 = (ss1 - sum1 * sum1 * (1.f/27.f)) * (1.f/26.f);
        float inv0 = 1.f / (1e-8f + 0.1f * sqrtf(fmaxf(var0, 0.f)));
        float inv1 = 1.f / (1e-8f + 0.1f * sqrtf(fmaxf(var1, 0.f)));
        #pragma unroll
        for (int k = 0; k < NTAP; ++k) {
            acc[2*k]   = fmaf(tmp[2*k],   -inv0, acc[2*k]);
            acc[2*k+1] = fmaf(tmp[2*k+1], -inv1, acc[2*k+1]);
        }
    }

    int pix = h * WW + w0;
    float* pb = partial + (size_t)(g * BB + b) * NTAP * NPIX + pix;
    #pragma unroll
    for (int k = 0; k < NTAP; ++k) {
        *((float2*)(pb + (size_t)k * NPIX)) = make_float2(acc[2*k], acc[2*k+1]);
    }
}

// ---- finalize: sum groups, mean over C, softmax over taps ------------------
__global__ __launch_bounds__(64) void finalize_affinity_kernel(
    const float* __restrict__ partial, float* __restrict__ aff, int G) {
    int idx = blockIdx.x * 64 + threadIdx.x;   // 0..65535
    int b = idx >> 14;
    int pix = idx & (NPIX - 1);
    float acc[NTAP];
    #pragma unroll
    for (int k = 0; k < NTAP; ++k) acc[k] = 0.f;
    for (int g = 0; g < G; ++g) {
        const float* pb = partial + (size_t)(g * BB + b) * NTAP * NPIX + pix;
        #pragma unroll
        for (int k = 0; k < NTAP; ++k) acc[k] += pb[(size_t)k * NPIX];
    }
    float m = -1e30f;
    #pragma unroll
    for (int k = 0; k < NTAP; ++k) { acc[k] *= (1.f/CC); m = fmaxf(m, acc[k]); }
    float s = 0.f;
    #pragma unroll
    for (int k = 0; k < NTAP; ++k) { acc[k] = expf(acc[k] - m); s += acc[k]; }
    float invs = 1.f / s;
    float* ab = aff + (size_t)b * NTAP * NPIX + pix;
    #pragma unroll
    for (int k = 0; k < NTAP; ++k) ab[(size_t)k * NPIX] = acc[k] * invs;
}

// ---- prop: 4 pixels x 3 channels per thread; aff in registers --------------
__global__ __launch_bounds__(128) void prop_kernel(
    const float* __restrict__ psrc_all, const float* __restrict__ aff,
    float* __restrict__ dst, int final_iter) {
    int t = blockIdx.x * 128 + threadIdx.x;   // 0..4095
    int cg = blockIdx.y;                       // 0..6
    int b = blockIdx.z;
    int w4 = t & 31;
    int w0 = w4 * 4;
    int h = t >> 5;

    const float* affp = aff + (size_t)b * NTAP * NPIX + h * WW + w0;
    float4 A[NTAP];
    #pragma unroll
    for (int k = 0; k < NTAP; ++k) A[k] = *((const float4*)(affp + (size_t)k * NPIX));

    float rb[12];

#define PLOADROW(dy) { \
    const float4* rp = (const float4*)(psrc + (size_t)(h + PAD + (dy)) * PW + w0); \
    float4 f0 = rp[0], f1 = rp[1], f2 = rp[2]; \
    rb[0]=f0.x; rb[1]=f0.y; rb[2]=f0.z; rb[3]=f0.w; \
    rb[4]=f1.x; rb[5]=f1.y; rb[6]=f1.z; rb[7]=f1.w; \
    rb[8]=f2.x; rb[9]=f2.y; rb[10]=f2.z; rb[11]=f2.w; }

#define PTAP(k, di) { \
    acc.x = fmaf(A[k].x, rb[(di)],   acc.x); \
    acc.y = fmaf(A[k].y, rb[(di)+1], acc.y); \
    acc.z = fmaf(A[k].z, rb[(di)+2], acc.z); \
    acc.w = fmaf(A[k].w, rb[(di)+3], acc.w); }

    #pragma unroll
    for (int cc = 0; cc < CG; ++cc) {
        int ch = cg * CG + cc;
        const float* psrc = psrc_all + (size_t)(b * CHN + ch) * PPLANE;
        float4 acc = make_float4(0.f, 0.f, 0.f, 0.f);

        PLOADROW(0);  PTAP(3,3)  PTAP(4,5)  PTAP(11,2) PTAP(12,6) PTAP(19,0) PTAP(20,8)
        PLOADROW(-1); PTAP(0,3)  PTAP(1,4)  PTAP(2,5)
        PLOADROW(1);  PTAP(5,3)  PTAP(6,4)  PTAP(7,5)
        PLOADROW(-2); PTAP(8,2)  PTAP(9,4)  PTAP(10,6)
        PLOADROW(2);  PTAP(13,2) PTAP(14,4) PTAP(15,6)
        PLOADROW(-4); PTAP(16,0) PTAP(17,4) PTAP(18,8)
        PLOADROW(4);  PTAP(21,0) PTAP(22,4) PTAP(23,8)

        if (final_iter) {
            *((float4*)(dst + (size_t)(b * CHN + ch) * NPIX + h * WW + w0)) = acc;
        } else {
            float4* pd = (float4*)(dst + (size_t)(b * CHN + ch) * PPLANE);
            pd[(h + PAD) * PWQ + w4 + 1] = acc;
            if (h == 0) {
                #pragma unroll
                for (int r = 0; r < PAD; ++r) pd[r * PWQ + w4 + 1] = acc;
            }
            if (h == HH - 1) {
                #pragma unroll
                for (int r = 0; r < PAD; ++r) pd[(PH - 1 - r) * PWQ + w4 + 1] = acc;
            }
            if (w4 == 0) {
                float4 e = make_float4(acc.x, acc.x, acc.x, acc.x);
                pd[(h + PAD) * PWQ] = e;
                if (h == 0) {
                    #pragma unroll
                    for (int r = 0; r < PAD; ++r) pd[r * PWQ] = e;
                }
                if (h == HH - 1) {
                    #pragma unroll
                    for (int r = 0; r < PAD; ++r) pd[(PH - 1 - r) * PWQ] = e;
                }
            }
            if (w4 == 31) {
                float4 e = make_float4(acc.w, acc.w, acc.w, acc.w);
                pd[(h + PAD) * PWQ + PWQ - 1] = e;
                if (h == 0) {
                    #pragma unroll
                    for (int r = 0; r < PAD; ++r) pd[r * PWQ + PWQ - 1] = e;
                }
                if (h == HH - 1) {
                    #pragma unroll
                    for (int r = 0; r < PAD; ++r) pd[(PH - 1 - r) * PWQ + PWQ - 1] = e;
                }
            }
        }
    }
}

extern "C" void kernel_launch(void* const* d_in, const int* in_sizes, int n_in,
                              void* d_out, int out_size, void* d_ws, size_t ws_size,
                              hipStream_t stream) {
    const float* feats = (const float*)d_in[0];
    const float* mask  = (const float*)d_in[1];
    float* out = (float*)d_out;

    const size_t affE    = (size_t)BB * NTAP * NPIX;    // 1.57 M floats
    const size_t pbufE   = (size_t)BB * CHN * PPLANE;   // 1.55 M floats
    const size_t pfeatsE = (size_t)BB * CC * PPLANE;    // 4.73 M floats

    float* aff     = (float*)d_ws;
    float* pbuf0   = aff + affE;
    float* pbuf1   = pbuf0 + pbufE;
    float* pfeats  = pbuf1 + pbufE;
    float* partial = pfeats + pfeatsE;

    size_t baseBytes = (affE + 2 * pbufE + pfeatsE) * sizeof(float);
    int G = 1;
    for (int g = 4; g >= 1; g >>= 1) {
        if (baseBytes + (size_t)g * affE * sizeof(float) <= ws_size) { G = g; break; }
    }

    {
        int total = (BB * CC + BB * CHN) * PH * PWQ;
        pad_kernel<<<dim3((total + 255) / 256), dim3(256), 0, stream>>>(feats, mask, pfeats, pbuf0);
    }
    partial_affinity_kernel<<<dim3(128, G), dim3(256), 0, stream>>>(pfeats, partial, CC / G);
    finalize_affinity_kernel<<<dim3(1024), dim3(64), 0, stream>>>(partial, aff, G);

    const float* src = pbuf0;
    for (int it = 1; it <= 10; ++it) {
        if (it < 10) {
            float* dst = (it & 1) ? pbuf1 : pbuf0;
            prop_kernel<<<dim3(32, NCG, BB), dim3(128), 0, stream>>>(src, aff, dst, 0);
            src = dst;
        } else {
            prop_kernel<<<dim3(32, NCG, BB), dim3(128), 0, stream>>>(src, aff, out, 1);
        }
    }
}